// Round 9
// baseline (151.837 us; speedup 1.0000x reference)
//
#include <hip/hip_runtime.h>

// Harness promotes float16 tensors to float32: x, scales, out are f32;
// weight_packed is int32, one byte (2 nibbles) per element.
#define M 32
#define N 11008
#define K 4096
#define NGROUPS 32
#define KSPLIT 16
#define KRANGE (K / KSPLIT)  // 256 k per block
#define NTILE 4              // n-tiles (of 64 rows) per block
#define MN (M * N)

typedef _Float16 half8 __attribute__((ext_vector_type(8))); // 4 VGPRs
typedef _Float16 half4 __attribute__((ext_vector_type(4)));
typedef float floatx4 __attribute__((ext_vector_type(4)));

#define WPAIR 260 // ints per 1KB weight row-pair + 16B pad (bank spread)

// s_waitcnt imms (gfx9/CDNA encoding): vmcnt[3:0]+[15:14], expcnt[6:4], lgkmcnt[11:8]
#define WAITVM8()   __builtin_amdgcn_s_waitcnt(0x0F78) // vmcnt(8), lgkm/exp free
#define WAITVM0()   __builtin_amdgcn_s_waitcnt(0x0F70) // vmcnt(0)
#define WAITLGKM0() __builtin_amdgcn_s_waitcnt(0xC07F) // lgkmcnt(0), vm/exp free

__device__ inline void gll16(const void* g, void* l) {
    __builtin_amdgcn_global_load_lds(
        (const __attribute__((address_space(1))) unsigned int*)g,
        (__attribute__((address_space(3))) unsigned int*)l, 16, 0, 0);
}

// ---- pre-pass: x f32 -> f16 (512 KB -> 256 KB in d_ws) ----
__global__ __launch_bounds__(512) void xcvt_kernel(
    const float* __restrict__ x, _Float16* __restrict__ xf)
{
    int i = (blockIdx.x * 512 + threadIdx.x) * 4; // M*K = 131072 = 64*512*4
    float4 v = *(const float4*)(x + i);
    half4 h;
    h[0] = (_Float16)v.x; h[1] = (_Float16)v.y;
    h[2] = (_Float16)v.z; h[3] = (_Float16)v.w;
    *(half4*)(xf + i) = h;
}

__global__ __launch_bounds__(256, 2) void int4_gemm_kernel(
    const _Float16* __restrict__ xf,  // [M][K] f16 (pre-converted)
    const int* __restrict__ wp,       // [N][K/2] int32, 2 nibbles each
    const float* __restrict__ scales, // [N][NGROUPS] f32
    float* __restrict__ part)         // [KSPLIT][M][N] f32 partials
{
    // Per-wave private double buffers: [wave][buf][8 pairs][WPAIR] = 66.6 KB
    __shared__ int wsh[4 * 2 * 8 * WPAIR];

    const int t     = threadIdx.x;
    const int lane  = t & 63;
    const int w     = t >> 6;
    const int ks    = blockIdx.x;          // k in [ks*256, ks*256+256)
    const int nbase = blockIdx.y * 256;    // 4 waves x 4 tiles x 16 rows
    const int row   = lane & 15;
    const int quad  = lane >> 4;
    const int k0    = ks * KRANGE;

    // ---- x fragments in registers: loop-invariant over n-tiles ----
    half8 af[8][2]; // [k-step][m-tile], 64 VGPRs
    #pragma unroll
    for (int kk = 0; kk < 8; ++kk)
        #pragma unroll
        for (int i = 0; i < 2; ++i)
            af[kk][i] = *(const half8*)(xf + (i * 16 + row) * K + k0 + kk * 32 + quad * 8);

    // ---- scales for all 4 tiles (so only gll lives in the loop's vmcnt) ----
    float sc[NTILE][2];
    #pragma unroll
    for (int tt = 0; tt < NTILE; ++tt) {
        int nw = nbase + tt * 64 + w * 16 + row;
        sc[tt][0] = scales[nw * NGROUPS + ks * 2];
        sc[tt][1] = scales[nw * NGROUPS + ks * 2 + 1];
    }

    // wave stages its own 16 rows of tile tt into its own buffer: 8 x 1KB gll
    auto stage = [&](int tt, int buf) {
        const long rbase = nbase + tt * 64 + w * 16;
        #pragma unroll
        for (int p = 0; p < 8; ++p) {
            const int* g = wp + (rbase + 2 * p + (lane >> 5)) * (long)(K / 2)
                         + ks * (KRANGE / 2) + (lane & 31) * 4;
            gll16(g, &wsh[((w * 2 + buf) * 8 + p) * WPAIR]);
        }
    };

    const half8 c1032 = (half8)(_Float16)1032.0f; // 0x6408, exact

    auto compute = [&](int tt, int buf) {
        floatx4 acc0 = {0.f, 0.f, 0.f, 0.f};
        floatx4 acc1 = {0.f, 0.f, 0.f, 0.f};
        const int wb = (w * 2 + buf) * 8 * WPAIR + (row >> 1) * WPAIR
                     + (row & 1) * 128 + quad * 4;
        #pragma unroll
        for (int g = 0; g < 2; ++g) {       // two 128-k scale groups
            floatx4 t0 = {0.f, 0.f, 0.f, 0.f};
            floatx4 t1 = {0.f, 0.f, 0.f, 0.f};
            #pragma unroll
            for (int k4 = 0; k4 < 4; ++k4) { // 4 MFMA k-steps of 32
                const int kq = g * 4 + k4;
                int4 wv = *(const int4*)&wsh[wb + kq * 16];
                uint4 uw;
                {
                    unsigned int b;
                    b = (unsigned int)wv.x; uw.x = ((b | (b << 12)) & 0x000F000Fu) | 0x64006400u;
                    b = (unsigned int)wv.y; uw.y = ((b | (b << 12)) & 0x000F000Fu) | 0x64006400u;
                    b = (unsigned int)wv.z; uw.z = ((b | (b << 12)) & 0x000F000Fu) | 0x64006400u;
                    b = (unsigned int)wv.w; uw.w = ((b | (b << 12)) & 0x000F000Fu) | 0x64006400u;
                }
                half8 bfrag = __builtin_bit_cast(half8, uw) - c1032; // exact (nib-8)
                t0 = __builtin_amdgcn_mfma_f32_16x16x32_f16(af[kq][0], bfrag, t0, 0, 0, 0);
                t1 = __builtin_amdgcn_mfma_f32_16x16x32_f16(af[kq][1], bfrag, t1, 0, 0, 0);
            }
            const float s = sc[tt][g];
            #pragma unroll
            for (int r = 0; r < 4; ++r) {
                acc0[r] += s * t0[r]; // fp32 scale application, matches reference
                acc1[r] += s * t1[r];
            }
        }
        // C/D layout: col(n)=lane&15, row(m)=quad*4+r. Coalesced 64B rows.
        float* po = part + (long)ks * MN;
        const int nw = nbase + tt * 64 + w * 16 + row;
        #pragma unroll
        for (int r = 0; r < 4; ++r) {
            int mr = quad * 4 + r;
            po[mr * N + nw]        = acc0[r];
            po[(mr + 16) * N + nw] = acc1[r];
        }
    };

    // ---- barrier-free per-wave software pipeline over 4 n-tiles ----
    stage(0, 0);
    stage(1, 1);
    WAITVM8();               // all but stage1's 8 gll done => stage0 + af + sc done
    compute(0, 0);
    WAITLGKM0();             // ds_reads of buf0 retired before overwrite
    stage(2, 0);
    WAITVM8();               // all but stage2 done => stage1, stores0 done
    compute(1, 1);
    WAITLGKM0();
    stage(3, 1);
    WAITVM8();               // all but stage3 done => stage2, stores1 done
    compute(2, 0);
    WAITVM0();               // drain all => stage3 done
    compute(3, 1);
}

// ---- reduce the 16 k-split partials -> out ----
__global__ __launch_bounds__(256) void reduce_kernel(
    const float* __restrict__ part, float* __restrict__ out)
{
    int o = blockIdx.x * 256 + threadIdx.x; // MN = 352256 = 1376*256
    float s = 0.f;
    #pragma unroll
    for (int j = 0; j < KSPLIT; ++j) s += part[(long)j * MN + o];
    out[o] = s;
}

extern "C" void kernel_launch(void* const* d_in, const int* in_sizes, int n_in,
                              void* d_out, int out_size, void* d_ws, size_t ws_size,
                              hipStream_t stream) {
    const float* x      = (const float*)d_in[0];
    const int* wp       = (const int*)d_in[1];
    const float* scales = (const float*)d_in[2];
    float* out          = (float*)d_out;

    _Float16* xf16 = (_Float16*)d_ws;                         // 256 KB
    float* part    = (float*)((char*)d_ws + (size_t)M * K * 2); // 22.5 MB

    xcvt_kernel<<<dim3((M * K) / (512 * 4)), 512, 0, stream>>>(x, xf16);
    int4_gemm_kernel<<<dim3(KSPLIT, N / 256), 256, 0, stream>>>(xf16, wp, scales, part);
    reduce_kernel<<<dim3(MN / 256), 256, 0, stream>>>(part, out);
}

// Round 10
// 149.793 us; speedup vs baseline: 1.0136x; 1.0136x over previous
//
#include <hip/hip_runtime.h>

// Harness promotes float16 tensors to float32: x, scales, out are f32;
// weight_packed is int32, one byte (2 nibbles) per element.
#define M 32
#define N 11008
#define K 4096
#define NGROUPS 32
#define KSPLIT 4             // k-split across blocks (atomic contenders per out)
#define KRANGE (K / KSPLIT)  // 1024 k per block
#define BK 256               // k per staged chunk (16 rows x 256 k weights)
#define NCHUNK (KRANGE / BK) // 4
#define MN (M * N)

typedef _Float16 half8 __attribute__((ext_vector_type(8))); // 4 VGPRs
typedef _Float16 half4 __attribute__((ext_vector_type(4)));
typedef float floatx4 __attribute__((ext_vector_type(4)));

#define WPAIR 260 // ints per 1KB weight row-pair + 16B pad

__device__ inline void gll16(const void* g, void* l) {
    __builtin_amdgcn_global_load_lds(
        (const __attribute__((address_space(1))) unsigned int*)g,
        (__attribute__((address_space(3))) unsigned int*)l, 16, 0, 0);
}

// ---- pre-pass: x f32 -> f16 (512 KB -> 256 KB in d_ws) ----
__global__ __launch_bounds__(512) void xcvt_kernel(
    const float* __restrict__ x, _Float16* __restrict__ xf)
{
    int i = (blockIdx.x * 512 + threadIdx.x) * 4; // M*K = 131072 = 64*512*4
    float4 v = *(const float4*)(x + i);
    half4 h;
    h[0] = (_Float16)v.x; h[1] = (_Float16)v.y;
    h[2] = (_Float16)v.z; h[3] = (_Float16)v.w;
    *(half4*)(xf + i) = h;
}

// block: 16 n-rows, 4 waves each owning a 64-k slice of each 256-k chunk.
// LDS = weights only (8.3 KB) -> 8 blocks/CU (wave cap), 32 waves/CU.
__global__ __launch_bounds__(256, 8) void int4_gemm_kernel(
    const _Float16* __restrict__ xf,  // [M][K] f16 (pre-converted)
    const int* __restrict__ wp,       // [N][K/2] int32, 2 nibbles each
    const float* __restrict__ scales, // [N][NGROUPS] f32
    float* __restrict__ out)          // [M][N] f32, pre-zeroed (atomic dest)
{
    __shared__ int wsh[8 * WPAIR]; // 16 weight rows as 8 pairs: 8.32 KB

    const int t    = threadIdx.x;
    const int lane = t & 63;
    const int w    = t >> 6;        // wave id: k-slice within chunk
    const int n0   = blockIdx.x * 16;
    const int ks   = blockIdx.y;    // k in [ks*1024, ks*1024+1024)
    const int row  = lane & 15;     // n-row of B / m-row of A
    const int quad = lane >> 4;
    const int nw   = n0 + row;      // this lane's weight row / output col

    const half8 c1032 = (half8)(_Float16)1032.0f; // 0x6408, exact
    floatx4 acc0 = {0.f, 0.f, 0.f, 0.f};
    floatx4 acc1 = {0.f, 0.f, 0.f, 0.f};

    for (int c = 0; c < NCHUNK; ++c) {
        const int k0 = ks * KRANGE + c * BK;

        // ---- stage 16 rows x 256 k of weights: 8 pairs x 1KB, 2 per wave ----
        #pragma unroll
        for (int i = 0; i < 2; ++i) {
            int p = w * 2 + i;
            int r = 2 * p + (lane >> 5);
            const int* g = wp + (long)(n0 + r) * (K / 2) + (k0 >> 1) + (lane & 31) * 4;
            gll16(g, &wsh[p * WPAIR]);
        }
        __syncthreads(); // drains gll queue; tile visible to all waves

        // ---- x fragments for this wave's 64-k slice, from L2-hot f16 x ----
        const int kw = k0 + w * 64;
        half8 a[2][2]; // [kk][m-tile] = 16 VGPRs
        #pragma unroll
        for (int kk = 0; kk < 2; ++kk)
            #pragma unroll
            for (int i = 0; i < 2; ++i)
                a[kk][i] = *(const half8*)(xf + (i * 16 + row) * K + kw + kk * 32 + quad * 8);

        // wave's 64-k slice lies in scale group (k0>>7) + (w>>1)
        const float s = scales[nw * NGROUPS + (k0 >> 7) + (w >> 1)];

        floatx4 t0 = {0.f, 0.f, 0.f, 0.f};
        floatx4 t1 = {0.f, 0.f, 0.f, 0.f};
        #pragma unroll
        for (int kk = 0; kk < 2; ++kk) {
            // 8 consecutive k of row 'row' at chunk-k w*64+kk*32
            int4 wv = *(const int4*)&wsh[(row >> 1) * WPAIR + (row & 1) * 128
                                         + w * 32 + kk * 16 + quad * 4];
            uint4 uw;
            {
                unsigned int b;
                b = (unsigned int)wv.x; uw.x = ((b | (b << 12)) & 0x000F000Fu) | 0x64006400u;
                b = (unsigned int)wv.y; uw.y = ((b | (b << 12)) & 0x000F000Fu) | 0x64006400u;
                b = (unsigned int)wv.z; uw.z = ((b | (b << 12)) & 0x000F000Fu) | 0x64006400u;
                b = (unsigned int)wv.w; uw.w = ((b | (b << 12)) & 0x000F000Fu) | 0x64006400u;
            }
            half8 bfrag = __builtin_bit_cast(half8, uw) - c1032; // exact (nib-8)
            t0 = __builtin_amdgcn_mfma_f32_16x16x32_f16(a[kk][0], bfrag, t0, 0, 0, 0);
            t1 = __builtin_amdgcn_mfma_f32_16x16x32_f16(a[kk][1], bfrag, t1, 0, 0, 0);
        }
        #pragma unroll
        for (int r = 0; r < 4; ++r) {
            acc0[r] += s * t0[r]; // fp32 scale application, matches reference
            acc1[r] += s * t1[r];
        }
        __syncthreads(); // WAR: ds_reads done before next stage / epilogue reuse
    }

    // ---- epilogue: reduce 4 waves' k-slices in LDS, 2 atomics per thread ----
    float* red = (float*)wsh; // 2048 f32 = 8 KB, fits in wsh
    #pragma unroll
    for (int r = 0; r < 4; ++r) {
        // C/D layout: col(n) = lane&15, row(m) = quad*4 + r
        red[w * 512 + (quad * 4 + r) * 16 + row]      = acc0[r];
        red[w * 512 + (quad * 4 + r + 16) * 16 + row] = acc1[r];
    }
    __syncthreads();
    #pragma unroll
    for (int i = 0; i < 2; ++i) {
        int o = t + 256 * i; // o = m*16 + n
        float sum = red[o] + red[512 + o] + red[1024 + o] + red[1536 + o];
        int m = o >> 4;
        int n = o & 15;
        atomicAdd(&out[m * N + n0 + n], sum);
    }
}

extern "C" void kernel_launch(void* const* d_in, const int* in_sizes, int n_in,
                              void* d_out, int out_size, void* d_ws, size_t ws_size,
                              hipStream_t stream) {
    const float* x      = (const float*)d_in[0];
    const int* wp       = (const int*)d_in[1];
    const float* scales = (const float*)d_in[2];
    float* out          = (float*)d_out;
    _Float16* xf16      = (_Float16*)d_ws; // 256 KB

    hipMemsetAsync(out, 0, (size_t)MN * sizeof(float), stream);
    xcvt_kernel<<<dim3((M * K) / (512 * 4)), 512, 0, stream>>>(x, xf16);
    int4_gemm_kernel<<<dim3(N / 16, KSPLIT), 256, 0, stream>>>(xf16, wp, scales, out);
}

// Round 11
// 149.221 us; speedup vs baseline: 1.0175x; 1.0038x over previous
//
#include <hip/hip_runtime.h>

// Harness promotes float16 tensors to float32: x, scales, out are f32;
// weight_packed is int32, one byte (2 nibbles) per element.
#define M 32
#define N 11008
#define K 4096
#define NGROUPS 32
#define KSPLIT 4             // k-split across blocks (atomic contenders per out)
#define KRANGE (K / KSPLIT)  // 1024 k per block
#define BK 256               // k per staged chunk
#define NCHUNK (KRANGE / BK) // 4
#define MN (M * N)

typedef _Float16 half8 __attribute__((ext_vector_type(8))); // 4 VGPRs
typedef _Float16 half4 __attribute__((ext_vector_type(4)));
typedef float floatx4 __attribute__((ext_vector_type(4)));

#define WROW 132 // ints per weight LDS row: 128 + 4 pad (528 B, 16B-aligned)
#define XROW 264 // halves per x LDS row:    256 + 8 pad (528 B, 16B-aligned)

// ---- pre-pass: x f32 -> f16 (512 KB -> 256 KB in d_ws) ----
__global__ __launch_bounds__(512) void xcvt_kernel(
    const float* __restrict__ x, _Float16* __restrict__ xf)
{
    int i = (blockIdx.x * 512 + threadIdx.x) * 4; // M*K = 131072 = 64*512*4
    float4 v = *(const float4*)(x + i);
    half4 h;
    h[0] = (_Float16)v.x; h[1] = (_Float16)v.y;
    h[2] = (_Float16)v.z; h[3] = (_Float16)v.w;
    *(half4*)(xf + i) = h;
}

// R6 structure; ONLY the staging path changed: buffer_load dwordx4 -> VGPR ->
// ds_write_b128 (deep VGPR-return queue) instead of global_load_lds (LDS-DMA
// queue, suspected ~64-line/CU cap -> 2.4 TB/s ceiling seen in R6-R10).
__global__ __launch_bounds__(256) void int4_gemm_kernel(
    const _Float16* __restrict__ xf,  // [M][K] f16 (pre-converted)
    const int* __restrict__ wp,       // [N][K/2] int32, 2 nibbles each
    const float* __restrict__ scales, // [N][NGROUPS] f32
    float* __restrict__ out)          // [M][N] f32, pre-zeroed (atomic dest)
{
    __shared__ __align__(16) int wsh[16 * WROW];      // 16 w-rows:  8.45 KB
    __shared__ __align__(16) _Float16 xs[32 * XROW];  // 32 x-rows: 16.9 KB

    const int t    = threadIdx.x;
    const int lane = t & 63;
    const int w    = t >> 6;        // wave id: k-slice within chunk
    const int n0   = blockIdx.x * 16;
    const int ks   = blockIdx.y;    // k in [ks*1024, ks*1024+1024)
    const int row  = lane & 15;     // n-row of B / m-row of A
    const int quad = lane >> 4;
    const int nw   = n0 + row;      // this lane's weight row / output col
    const int half32 = lane >> 5;   // which row of a staged pair
    const int l32  = lane & 31;

    const half8 c1032 = (half8)(_Float16)1032.0f; // 0x6408, exact
    floatx4 acc0 = {0.f, 0.f, 0.f, 0.f};
    floatx4 acc1 = {0.f, 0.f, 0.f, 0.f};

    for (int c = 0; c < NCHUNK; ++c) {
        const int k0 = ks * KRANGE + c * BK;

        // ---- stage weights 16 rows x 256 k: 2 insts/wave, lane-contiguous ----
        int4 wv0, wv1;
        {
            int r0 = w * 4 + half32;       // rows w*4 .. w*4+3
            int r1 = r0 + 2;
            wv0 = *(const int4*)(wp + (long)(n0 + r0) * (K / 2) + (k0 >> 1) + l32 * 4);
            wv1 = *(const int4*)(wp + (long)(n0 + r1) * (K / 2) + (k0 >> 1) + l32 * 4);
        }
        // ---- stage x 32 rows x 256 k: 4 insts/wave, lane-contiguous ----
        uint4 xv[4];
        #pragma unroll
        for (int i = 0; i < 4; ++i) {
            int m = w * 8 + i * 2 + half32; // rows w*8 .. w*8+7
            xv[i] = *(const uint4*)(xf + m * K + k0 + l32 * 8);
        }
        // VGPR -> LDS (compiler inserts vmcnt waits as loads return)
        {
            int r0 = w * 4 + half32, r1 = r0 + 2;
            *(int4*)&wsh[r0 * WROW + l32 * 4] = wv0;
            *(int4*)&wsh[r1 * WROW + l32 * 4] = wv1;
        }
        #pragma unroll
        for (int i = 0; i < 4; ++i) {
            int m = w * 8 + i * 2 + half32;
            *(uint4*)&xs[m * XROW + l32 * 8] = xv[i];
        }
        __syncthreads(); // tile visible to all waves

        // ---- compute: wave w owns chunk-k slice [w*64, w*64+64) ----
        const float s = scales[nw * NGROUPS + (k0 >> 7) + (w >> 1)];
        floatx4 t0 = {0.f, 0.f, 0.f, 0.f};
        floatx4 t1 = {0.f, 0.f, 0.f, 0.f};
        #pragma unroll
        for (int kk = 0; kk < 2; ++kk) {
            int4 wv = *(const int4*)&wsh[row * WROW + w * 32 + kk * 16 + quad * 4];
            uint4 uw;
            {
                unsigned int b;
                b = (unsigned int)wv.x; uw.x = ((b | (b << 12)) & 0x000F000Fu) | 0x64006400u;
                b = (unsigned int)wv.y; uw.y = ((b | (b << 12)) & 0x000F000Fu) | 0x64006400u;
                b = (unsigned int)wv.z; uw.z = ((b | (b << 12)) & 0x000F000Fu) | 0x64006400u;
                b = (unsigned int)wv.w; uw.w = ((b | (b << 12)) & 0x000F000Fu) | 0x64006400u;
            }
            half8 bfrag = __builtin_bit_cast(half8, uw) - c1032; // exact (nib-8)
            half8 a0 = *(const half8*)&xs[row * XROW + w * 64 + kk * 32 + quad * 8];
            half8 a1 = *(const half8*)&xs[(row + 16) * XROW + w * 64 + kk * 32 + quad * 8];
            t0 = __builtin_amdgcn_mfma_f32_16x16x32_f16(a0, bfrag, t0, 0, 0, 0);
            t1 = __builtin_amdgcn_mfma_f32_16x16x32_f16(a1, bfrag, t1, 0, 0, 0);
        }
        #pragma unroll
        for (int r = 0; r < 4; ++r) {
            acc0[r] += s * t0[r]; // fp32 scale application, matches reference
            acc1[r] += s * t1[r];
        }
        __syncthreads(); // WAR: ds_reads done before next stage / epilogue reuse
    }

    // ---- epilogue: reduce 4 waves' k-slices in LDS, 2 atomics per thread ----
    float* red = (float*)xs; // 8 KB, xs no longer needed
    #pragma unroll
    for (int r = 0; r < 4; ++r) {
        // C/D layout: col(n) = lane&15, row(m) = quad*4 + r
        red[w * 512 + (quad * 4 + r) * 16 + row]      = acc0[r];
        red[w * 512 + (quad * 4 + r + 16) * 16 + row] = acc1[r];
    }
    __syncthreads();
    #pragma unroll
    for (int i = 0; i < 2; ++i) {
        int o = t + 256 * i; // o = m*16 + n
        float sum = red[o] + red[512 + o] + red[1024 + o] + red[1536 + o];
        int m = o >> 4;
        int n = o & 15;
        atomicAdd(&out[m * N + n0 + n], sum);
    }
}

extern "C" void kernel_launch(void* const* d_in, const int* in_sizes, int n_in,
                              void* d_out, int out_size, void* d_ws, size_t ws_size,
                              hipStream_t stream) {
    const float* x      = (const float*)d_in[0];
    const int* wp       = (const int*)d_in[1];
    const float* scales = (const float*)d_in[2];
    float* out          = (float*)d_out;
    _Float16* xf16      = (_Float16*)d_ws; // 256 KB

    hipMemsetAsync(out, 0, (size_t)MN * sizeof(float), stream);
    xcvt_kernel<<<dim3((M * K) / (512 * 4)), 512, 0, stream>>>(x, xf16);
    int4_gemm_kernel<<<dim3(N / 16, KSPLIT), 256, 0, stream>>>(xf16, wp, scales, out);
}